// Round 13
// baseline (133.642 us; speedup 1.0000x reference)
//
#include <hip/hip_runtime.h>

// Problem constants (reference: B,T,D,O = 16,1024,1024,10; T==D required)
#define BB 16
#define TT 1024
#define DD 1024
#define OO 10

// ---------------------------------------------------------------------------
// Two kernels, K2 eliminated algebraically (max-free softmax):
//   K1: u[b,o,t] = exp((X[b,t,:].W[o,:] + b_o)/10); Z[b,o] = sum_t u
//   K3: out[b,o,t] = (X[b,t,:].u[b,:,o]) / Z[b,o]  (normalizer factors out)
//
// R13 change (single variable vs R10 best=120.3): TLP. 512-thread blocks
// (8 waves) with each wave owning D/8 = 128 floats (4 inner steps), same
// 32-row tiles, same grid (T/32, B) -> 16 waves/CU instead of 8. Theory:
// the ~8 us/pass latency exposure persists across every per-wave ILP change
// (depth-2/4, NT, LDS staging) because at 2 waves/SIMD there is almost no
// alternate wave to cover a vmcnt stall; doubling resident waves halves
// exposure without touching the proven loop body.
//   LDS: 40 KB W + 10 KB part + 1.25 KB uv = 51.25 KB -> 3 blocks/CU
//   capacity >= 2 needed. VGPR ~90 (R10 measured 88) < 128 -> 4 waves/SIMD.
//
// Mapping: wave w (0..7) owns d-slice [w*128,(w+1)*128); lane = g*8+l:
// group g owns rows t0+g+8j (j=0..3), slice l owns d = w*128+it*32+l*4.
// Depth-2 x prefetch, unroll-1 outer, 8-lane dots -> 3 __shfl_down(w=8),
// cross-wave combine of 8 partials via LDS.
//
// Refuted list: occupancy-hint bounds (R2 spill), per-chunk barriers (R6),
// device-barrier fusion (R8), softmax fold (R9), NT loads (R11),
// depth-4 banks (R12). Keep: R10 u/Z algebra (absmax even improved).
// ---------------------------------------------------------------------------
template <bool FIRST>
__global__ __launch_bounds__(512) void gemm10_kernel(
    const float* __restrict__ X,     // (B,T,D) logits
    const float* __restrict__ Wt,    // FIRST: W (O,D); else u (B,O,T)
    const float* __restrict__ bias,  // FIRST only
    float* __restrict__ Y,           // FIRST: u (B,O,T); else out (B,O,T)
    float* __restrict__ Z)           // (B,O): FIRST accumulates, else reads
{
    __shared__ float4 sW4[OO * 256];    // 40 KB operand ([o][t4])
    __shared__ float  part[8][32][OO];  // 10 KB
    __shared__ float  uv[32][OO];       // 1.25 KB (K1 epilogue reduce)

    const int b   = blockIdx.y;
    const int t0  = blockIdx.x * 32;
    const int tid = threadIdx.x;

    // ---- stage operand -> LDS (2560 float4, 5 per thread, coalesced) ----
    {
        const float4* src = (const float4*)(Wt + (FIRST ? 0 : (size_t)b * OO * TT));
#pragma unroll
        for (int c = 0; c < 5; ++c)
            sW4[c * 512 + tid] = src[c * 512 + tid];
    }
    __syncthreads();

    const int w    = tid >> 6;       // wave 0..7 -> d eighth
    const int lane = tid & 63;
    const int l    = lane & 7;       // d-slice within row
    const int g    = lane >> 3;      // row group 0..7
    const int dofs = w * 128 + l * 4;

    const float* xp[4];
#pragma unroll
    for (int j = 0; j < 4; ++j)
        xp[j] = X + ((size_t)b * TT + t0 + g + 8 * j) * DD + dofs;
    const float* sWl = (const float*)sW4 + dofs;

    float acc[4][OO];
#pragma unroll
    for (int j = 0; j < 4; ++j)
#pragma unroll
        for (int o = 0; o < OO; ++o) acc[j][o] = 0.f;

    // 2-deep prefetch of the logits slices (4 steps total per wave)
    float4 x0[4], x1[4];
#pragma unroll
    for (int j = 0; j < 4; ++j) {
        x0[j] = *(const float4*)(xp[j]);
        x1[j] = *(const float4*)(xp[j] + 32);
    }

#pragma unroll 1
    for (int it = 0; it < 4; it += 2) {
        float4 c0[4];
#pragma unroll
        for (int j = 0; j < 4; ++j) c0[j] = x0[j];
        if (it < 2) {
#pragma unroll
            for (int j = 0; j < 4; ++j)
                x0[j] = *(const float4*)(xp[j] + (it + 2) * 32);
        }
        {
            const float* wp = sWl + it * 32;
#pragma unroll
            for (int o = 0; o < OO; ++o) {
                const float4 wv = *(const float4*)(wp + o * DD);
#pragma unroll
                for (int j = 0; j < 4; ++j)
                    acc[j][o] += c0[j].x * wv.x + c0[j].y * wv.y +
                                 c0[j].z * wv.z + c0[j].w * wv.w;
            }
        }
#pragma unroll
        for (int j = 0; j < 4; ++j) c0[j] = x1[j];
        if (it < 1) {
#pragma unroll
            for (int j = 0; j < 4; ++j)
                x1[j] = *(const float4*)(xp[j] + (it + 3) * 32);
        }
        {
            const float* wp = sWl + (it + 1) * 32;
#pragma unroll
            for (int o = 0; o < OO; ++o) {
                const float4 wv = *(const float4*)(wp + o * DD);
#pragma unroll
                for (int j = 0; j < 4; ++j)
                    acc[j][o] += c0[j].x * wv.x + c0[j].y * wv.y +
                                 c0[j].z * wv.z + c0[j].w * wv.w;
            }
        }
    }

    // 3-level reduction within each 8-lane group, then cross-wave via LDS.
#pragma unroll
    for (int j = 0; j < 4; ++j) {
#pragma unroll
        for (int o = 0; o < OO; ++o) {
            float v = acc[j][o];
            v += __shfl_down(v, 4, 8);
            v += __shfl_down(v, 2, 8);
            v += __shfl_down(v, 1, 8);
            if (l == 0) part[w][j * 8 + g][o] = v;
        }
    }
    __syncthreads();

    // 32 rows x 10 o = 320 outputs; 512 threads -> tid < 320 writes one
    if (tid < 32 * OO) {
        const int row = tid / OO;
        const int o   = tid % OO;
        float v = 0.f;
#pragma unroll
        for (int ww = 0; ww < 8; ++ww) v += part[ww][row][o];
        if (FIRST) {
            // u = exp((dot + bias)/O); |arg| < ~0.5 -> max-free exp is safe
            float u = __expf((v + bias[o]) * (1.0f / OO));
            Y[((size_t)b * OO + o) * TT + (t0 + row)] = u;
            uv[row][o] = u;
        } else {
            const float invZ = 1.0f / Z[b * OO + o];
            Y[((size_t)b * OO + o) * TT + (t0 + row)] = v * invZ;
        }
    }

    if (FIRST) {
        __syncthreads();
        if (tid < OO) {
            float s = 0.f;
#pragma unroll
            for (int row = 0; row < 32; ++row) s += uv[row][tid];
            atomicAdd(&Z[b * OO + tid], s);   // device-scope by default
        }
    }
}

extern "C" void kernel_launch(void* const* d_in, const int* in_sizes, int n_in,
                              void* d_out, int out_size, void* d_ws, size_t ws_size,
                              hipStream_t stream)
{
    const float* logits = (const float*)d_in[0];
    // d_in[1] = decision — unused by the forward math
    const float* W    = (const float*)d_in[2];
    const float* bias = (const float*)d_in[3];
    float* out = (float*)d_out;

    float* u = (float*)d_ws;                         // B*O*T floats = 2.62 MB
    float* Z = (float*)((char*)d_ws + (4 << 20));    // B*O floats = 640 B

    // ws is poisoned 0xAA before every call -> zero the Z accumulators
    (void)hipMemsetAsync(Z, 0, BB * OO * sizeof(float), stream);

    dim3 grid(TT / 32, BB);
    // K1: u = exp((X.W^T + b)/O), Z = sum_t u   (kernel boundary = fence)
    gemm10_kernel<true><<<grid, 512, 0, stream>>>(logits, W, bias, u, Z);
    // K3: out = (X . u) * (1/Z)
    gemm10_kernel<false><<<grid, 512, 0, stream>>>(logits, u, nullptr, out, Z);
}

// Round 14
// 120.286 us; speedup vs baseline: 1.1110x; 1.1110x over previous
//
#include <hip/hip_runtime.h>

// Problem constants (reference: B,T,D,O = 16,1024,1024,10; T==D required)
#define BB 16
#define TT 1024
#define DD 1024
#define OO 10

// ---------------------------------------------------------------------------
// Two kernels, K2 + Z-pass eliminated algebraically (max-free softmax):
//   K1: u[b,o,t] = exp((X[b,t,:].W[o,:] + b_o)/10)        (scores sd~0.064
//       -> exp safe without max-subtraction; u/Z == reference softmax)
//   K3: stages the full u[b] slab (10x1024 = 40 KB) into LDS, computes
//       Z[b,o] = sum_t u IN-BLOCK from the slab (no global Z, no memset,
//       no atomics), then out[b,o,t] = (X[b,t,:].u[b,:,o]) / Z[b,o].
//
// Gemm body = R5/R10 proven mapping (best: 120.3 us total): grid (T/32, B),
// 4 waves, 32 rows/block; operand (W or u-slab) in LDS [o][t4] read as
// 8-address broadcast float4; lane = g*8+l of wave w: group g owns rows
// t0+g+8j (j=0..3), slice l owns d = w*256+it*32+l*4; depth-2 x prefetch;
// unroll-1 outer; 8-lane dots -> 3 __shfl_down(w=8) + LDS cross-wave combine.
//
// Refuted (do not retry): occupancy-hint bounds (R2 spill), per-chunk LDS
// staging barriers (R6), device-barrier fusion (R8), per-block softmax fold
// (R9), non-temporal X loads (R11), depth-4 prefetch banks (R12), 8-wave
// 512-thread blocks (R13). The R10 loop at ~19 us/pass (~3.5 TB/s) is the
// DRAM-efficiency plateau for the 8x128B-per-4KB read pattern.
// ---------------------------------------------------------------------------
template <bool FIRST>
__global__ __launch_bounds__(256) void gemm10_kernel(
    const float* __restrict__ X,     // (B,T,D) logits
    const float* __restrict__ Wt,    // FIRST: W (O,D); else u (B,O,T)
    const float* __restrict__ bias,  // FIRST only
    float* __restrict__ Y)           // FIRST: u (B,O,T); else out (B,O,T)
{
    __shared__ float4 sW4[OO * 256];    // 40 KB operand ([o][t4])
    __shared__ float  part[4][32][OO];  // 5 KB
    __shared__ float  zred[OO];         // 40 B (K3: per-batch softmax denom)

    const int b   = blockIdx.y;
    const int t0  = blockIdx.x * 32;
    const int tid = threadIdx.x;

    // ---- stage operand -> LDS (2560 float4, contiguous, coalesced) ----
    {
        const float4* src = (const float4*)(Wt + (FIRST ? 0 : (size_t)b * OO * TT));
#pragma unroll
        for (int c = 0; c < 10; ++c)
            sW4[c * 256 + tid] = src[c * 256 + tid];
    }
    __syncthreads();

    const int w    = tid >> 6;       // wave 0..3 -> d quarter
    const int lane = tid & 63;
    const int l    = lane & 7;       // d-slice within row
    const int g    = lane >> 3;      // row group 0..7
    const int dofs = w * 256 + l * 4;

    if (!FIRST) {
        // Z[b,o] = sum_t u from the staged slab. Wave w handles o = w+4k.
        // Visibility of zred at the epilogue is covered by the pre-epilogue
        // __syncthreads.
#pragma unroll
        for (int k = 0; k < 3; ++k) {
            const int o = w + 4 * k;
            if (o < OO) {
                float s = 0.f;
#pragma unroll
                for (int q = 0; q < 4; ++q) {
                    const float4 v = sW4[o * 256 + lane * 4 + q];
                    s += v.x + v.y + v.z + v.w;
                }
#pragma unroll
                for (int off = 32; off > 0; off >>= 1)
                    s += __shfl_down(s, off, 64);
                if (lane == 0) zred[o] = s;
            }
        }
    }

    const float* xp[4];
#pragma unroll
    for (int j = 0; j < 4; ++j)
        xp[j] = X + ((size_t)b * TT + t0 + g + 8 * j) * DD + dofs;
    const float* sWl = (const float*)sW4 + dofs;

    float acc[4][OO];
#pragma unroll
    for (int j = 0; j < 4; ++j)
#pragma unroll
        for (int o = 0; o < OO; ++o) acc[j][o] = 0.f;

    // 2-deep prefetch of the logits slices
    float4 x0[4], x1[4];
#pragma unroll
    for (int j = 0; j < 4; ++j) {
        x0[j] = *(const float4*)(xp[j]);
        x1[j] = *(const float4*)(xp[j] + 32);
    }

#pragma unroll 1
    for (int it = 0; it < 8; it += 2) {
        float4 c0[4];
#pragma unroll
        for (int j = 0; j < 4; ++j) c0[j] = x0[j];
        if (it < 6) {
#pragma unroll
            for (int j = 0; j < 4; ++j)
                x0[j] = *(const float4*)(xp[j] + (it + 2) * 32);
        }
        {
            const float* wp = sWl + it * 32;
#pragma unroll
            for (int o = 0; o < OO; ++o) {
                const float4 wv = *(const float4*)(wp + o * DD);
#pragma unroll
                for (int j = 0; j < 4; ++j)
                    acc[j][o] += c0[j].x * wv.x + c0[j].y * wv.y +
                                 c0[j].z * wv.z + c0[j].w * wv.w;
            }
        }
#pragma unroll
        for (int j = 0; j < 4; ++j) c0[j] = x1[j];
        if (it < 5) {
#pragma unroll
            for (int j = 0; j < 4; ++j)
                x1[j] = *(const float4*)(xp[j] + (it + 3) * 32);
        }
        {
            const float* wp = sWl + (it + 1) * 32;
#pragma unroll
            for (int o = 0; o < OO; ++o) {
                const float4 wv = *(const float4*)(wp + o * DD);
#pragma unroll
                for (int j = 0; j < 4; ++j)
                    acc[j][o] += c0[j].x * wv.x + c0[j].y * wv.y +
                                 c0[j].z * wv.z + c0[j].w * wv.w;
            }
        }
    }

    // 3-level reduction within each 8-lane group, then cross-wave via LDS.
#pragma unroll
    for (int j = 0; j < 4; ++j) {
#pragma unroll
        for (int o = 0; o < OO; ++o) {
            float v = acc[j][o];
            v += __shfl_down(v, 4, 8);
            v += __shfl_down(v, 2, 8);
            v += __shfl_down(v, 1, 8);
            if (l == 0) part[w][j * 8 + g][o] = v;
        }
    }
    __syncthreads();

    // 32 rows x 10 o = 320 outputs
    for (int idx = tid; idx < 32 * OO; idx += 256) {
        const int row = idx / OO;
        const int o   = idx % OO;
        float v = part[0][row][o] + part[1][row][o] +
                  part[2][row][o] + part[3][row][o];
        if (FIRST) {
            // u = exp((dot + bias)/O); |arg| < ~0.5 -> max-free exp is safe
            Y[((size_t)b * OO + o) * TT + (t0 + row)] =
                __expf((v + bias[o]) * (1.0f / OO));
        } else {
            Y[((size_t)b * OO + o) * TT + (t0 + row)] = v / zred[o];
        }
    }
}

extern "C" void kernel_launch(void* const* d_in, const int* in_sizes, int n_in,
                              void* d_out, int out_size, void* d_ws, size_t ws_size,
                              hipStream_t stream)
{
    const float* logits = (const float*)d_in[0];
    // d_in[1] = decision — unused by the forward math
    const float* W    = (const float*)d_in[2];
    const float* bias = (const float*)d_in[3];
    float* out = (float*)d_out;
    float* u   = (float*)d_ws;      // B*O*T floats = 2.62 MB

    dim3 grid(TT / 32, BB);
    // K1: u = exp((X.W^T + b)/O)   (kernel boundary = fence)
    gemm10_kernel<true><<<grid, 256, 0, stream>>>(logits, W, bias, u);
    // K3: Z computed in-block from the staged slab; out = (X.u) / Z
    gemm10_kernel<false><<<grid, 256, 0, stream>>>(logits, u, nullptr, out);
}